// Round 5
// baseline (571.613 us; speedup 1.0000x reference)
//
#include <hip/hip_runtime.h>
#include <hip/hip_fp16.h>
#include <math.h>
#include <stdint.h>

// GCNConv(256 -> 1, edge_weight, self-loops, sym-norm) + Mish.
// N = 200000, E = 12.8M, F = 256.
//
// Round-8 recap: reverted the global-atomic deg fusion (never per-edge
// device-scope atomics at E=12.8M: cross-XCD coherence => ~32B HBM RMW
// per edge). 8-wide bucket passes + SEG 32 were ~neutral (-7 us) =>
// bucket passes are not gather-MLP limited. 571 us total.
//
// Round 9: attack k_partition's same-address LDS atomic serialization.
// Histogram + placement each do 12.8M atomicAdds onto only 49 LDS words
// shared by 512 threads. Fix: per-wave replicas whist[8][64] (contention
// /8, intra-wave only), per-bucket prefix over waves gives each wave a
// private contiguous sub-run -> placement is still an exact counting
// sort. +2 KB LDS (39.8 KB, still 4 blocks/CU). Everything else
// byte-identical to round 8.
//
//   0: zero g_cnt
//   A: h[n] = dot(x[n,:], W)                  (wave per node)
//   P: partition edges into 49 buckets        (per-wave LDS counting sort)
//   D: (bkt,seg): LDS acc += attr             -> rep[seg]   (plain store)
//   N: dis = rsqrt(1 + sum_seg rep); g = dis*h
//   S: (bkt,seg): LDS acc += attr * g[row]    -> rep[seg]   (reused)
//   F: out = mish(dis*(sum_seg rep + g) + b)

#define NFEAT 256
#define SPAN 4096
#define SPAN_BITS 12
#define MAXBKT 64
#define SEG 32
#define BCAP 266240            // mean 262144 + ~8 sigma (mult of 8)
#define TILE 6144              // edges per partition block (LDS-sorted tile)
#define PBT 512                // partition block threads
#define PWAVES (PBT / 64)      // 8 waves per partition block
#define BBT 512                // bucket-pass block threads

__global__ void k_zero_u32(unsigned* __restrict__ p, int n) {
    int i = blockIdx.x * blockDim.x + threadIdx.x;
    if (i < n) p[i] = 0u;
}

__global__ void k_matvec(const float* __restrict__ x,
                         const float* __restrict__ W,
                         float* __restrict__ h, int N) {
    int gid  = blockIdx.x * blockDim.x + threadIdx.x;
    int node = gid >> 6;          // one 64-lane wave per node
    int lane = gid & 63;
    if (node >= N) return;
    float4 xv = ((const float4*)(x + (size_t)node * NFEAT))[lane];
    float4 wv = ((const float4*)W)[lane];
    float s = xv.x * wv.x + xv.y * wv.y + xv.z * wv.z + xv.w * wv.w;
#pragma unroll
    for (int off = 32; off > 0; off >>= 1)
        s += __shfl_down(s, off, 64);
    if (lane == 0) h[node] = s;
}

// Block-local counting sort with PER-WAVE histograms/cursors + coalesced
// run flush. LDS: lkey 24 KB + latt 12 KB + whist 2 KB + small ~0.8 KB
// -> ~39.8 KB => 4 blocks/CU x 512 thr = 2048 threads/CU (full).
__global__ void __launch_bounds__(PBT) k_partition(
        const int* __restrict__ row, const int* __restrict__ col,
        const float* __restrict__ attrs,
        unsigned* __restrict__ g_cnt,
        unsigned* __restrict__ keys, __half* __restrict__ att16,
        int E, int nbkt) {
    __shared__ unsigned whist[PWAVES][MAXBKT];  // counts -> wave cursors
    __shared__ unsigned lhist[MAXBKT];          // block totals
    __shared__ unsigned lstart[MAXBKT];         // block-local run starts
    __shared__ unsigned lbase[MAXBKT];          // global run bases
    __shared__ unsigned lkey[TILE];
    __shared__ unsigned short latt[TILE];

    const int tid  = threadIdx.x;
    const int wave = tid >> 6;
    const int e0   = blockIdx.x * TILE;
    const int e1   = min(e0 + TILE, E);
    const int nv   = (e1 - e0) & ~3;     // vectorizable prefix (mult of 4)

    ((unsigned*)whist)[tid] = 0u;        // PBT==PWAVES*MAXBKT
    __syncthreads();
    // Pass 1: per-wave histogram (int4 col reads; atomics intra-wave only).
    unsigned* myh = whist[wave];
    for (int o = tid << 2; o < nv; o += PBT << 2) {
        int4 c4 = *(const int4*)(col + e0 + o);
        atomicAdd(&myh[((unsigned)c4.x) >> SPAN_BITS], 1u);
        atomicAdd(&myh[((unsigned)c4.y) >> SPAN_BITS], 1u);
        atomicAdd(&myh[((unsigned)c4.z) >> SPAN_BITS], 1u);
        atomicAdd(&myh[((unsigned)c4.w) >> SPAN_BITS], 1u);
    }
    for (int e = e0 + nv + tid; e < e1; e += PBT)
        atomicAdd(&myh[((unsigned)col[e]) >> SPAN_BITS], 1u);
    __syncthreads();
    // Per-bucket exclusive prefix over waves; whist[w][b] -> wave-local
    // start, lhist[b] -> block total. Thread b owns column b.
    if (tid < MAXBKT) {
        unsigned s = 0;
#pragma unroll
        for (int w = 0; w < PWAVES; ++w) {
            unsigned c = whist[w][tid];
            whist[w][tid] = s;
            s += c;
        }
        lhist[tid] = s;
    }
    __syncthreads();
    if (tid == 0) {                       // 49-element serial prefix: cheap
        unsigned s = 0;
        for (int b = 0; b < nbkt; ++b) { lstart[b] = s; s += lhist[b]; }
    }
    if (tid < nbkt) lbase[tid] = atomicAdd(&g_cnt[tid], lhist[tid]);
    __syncthreads();
    // Turn whist into absolute per-wave cursors.
    if ((tid & 63) < nbkt) whist[wave][tid & 63] += lstart[tid & 63];
    __syncthreads();

    // Pass 2: scatter into LDS via private wave cursors.
    for (int o = tid << 2; o < nv; o += PBT << 2) {
        const int e = e0 + o;
        int4   c4 = *(const int4*)(col + e);
        int4   r4 = *(const int4*)(row + e);
        float4 a4 = *(const float4*)(attrs + e);
        {
            unsigned c = (unsigned)c4.x, bkt = c >> SPAN_BITS;
            unsigned t = atomicAdd(&myh[bkt], 1u);
            lkey[t] = ((unsigned)r4.x << SPAN_BITS) | (c & (SPAN - 1));
            latt[t] = __half_as_ushort(__float2half(a4.x));
        }
        {
            unsigned c = (unsigned)c4.y, bkt = c >> SPAN_BITS;
            unsigned t = atomicAdd(&myh[bkt], 1u);
            lkey[t] = ((unsigned)r4.y << SPAN_BITS) | (c & (SPAN - 1));
            latt[t] = __half_as_ushort(__float2half(a4.y));
        }
        {
            unsigned c = (unsigned)c4.z, bkt = c >> SPAN_BITS;
            unsigned t = atomicAdd(&myh[bkt], 1u);
            lkey[t] = ((unsigned)r4.z << SPAN_BITS) | (c & (SPAN - 1));
            latt[t] = __half_as_ushort(__float2half(a4.z));
        }
        {
            unsigned c = (unsigned)c4.w, bkt = c >> SPAN_BITS;
            unsigned t = atomicAdd(&myh[bkt], 1u);
            lkey[t] = ((unsigned)r4.w << SPAN_BITS) | (c & (SPAN - 1));
            latt[t] = __half_as_ushort(__float2half(a4.w));
        }
    }
    for (int e = e0 + nv + tid; e < e1; e += PBT) {
        unsigned c   = (unsigned)col[e];
        unsigned bkt = c >> SPAN_BITS;
        unsigned t   = atomicAdd(&myh[bkt], 1u);
        lkey[t] = ((unsigned)row[e] << SPAN_BITS) | (c & (SPAN - 1));
        latt[t] = __half_as_ushort(__float2half(attrs[e]));
    }
    __syncthreads();

    // Flush runs: wave w handles buckets w, w+8, ... Each run (~125 edges)
    // is a contiguous LDS->global copy: 256 B key chunks + 128 B att chunks.
    const int lane = tid & 63;
    for (int b = wave; b < nbkt; b += PWAVES) {
        const unsigned cnt = lhist[b];
        const unsigned gb  = lbase[b];
        const unsigned ls  = lstart[b];
        const size_t base  = (size_t)b * BCAP;
        for (unsigned i = lane; i < cnt; i += 64) {
            unsigned t = gb + i;
            if (t < BCAP) {              // never hit for this input; OOB guard
                keys[base + t]  = lkey[ls + i];
                att16[base + t] = __ushort_as_half(latt[ls + i]);
            }
        }
    }
}

// grid: (SEG, nbkt). 8 edges/thread/iter. Segment bounds padded to x8 so
// uint4 loads stay aligned. rep layout: rep[seg * npad + node].
__global__ void __launch_bounds__(BBT) k_bucket_deg(
        const unsigned* __restrict__ g_cnt, const unsigned* __restrict__ keys,
        const __half* __restrict__ att16, float* __restrict__ rep, int npad) {
    __shared__ float acc[SPAN];
    const int seg = blockIdx.x, bkt = blockIdx.y, tid = threadIdx.x;
#pragma unroll
    for (int j = tid; j < SPAN; j += BBT) acc[j] = 0.f;
    __syncthreads();
    const unsigned cnt = min(g_cnt[bkt], (unsigned)BCAP);
    const unsigned per = (((cnt + SEG - 1) / SEG) + 7u) & ~7u;   // x8-aligned
    const unsigned i0 = seg * per, i1 = min(cnt, i0 + per);
    const size_t base = (size_t)bkt * BCAP;
    if (i1 > i0) {
        const unsigned count = i1 - i0;
        const unsigned nvec  = count & ~7u;
        const unsigned* kp = keys + base + i0;
        const unsigned short* ap = (const unsigned short*)att16 + base + i0;
        for (unsigned o = tid << 3; o < nvec; o += BBT << 3) {
            uint4 ka = *(const uint4*)(kp + o);
            uint4 kb = *(const uint4*)(kp + o + 4);
            uint4 av = *(const uint4*)(const void*)(ap + o);   // 8 halves
            atomicAdd(&acc[ka.x & (SPAN - 1)],
                      __half2float(__ushort_as_half((unsigned short)(av.x & 0xffffu))));
            atomicAdd(&acc[ka.y & (SPAN - 1)],
                      __half2float(__ushort_as_half((unsigned short)(av.x >> 16))));
            atomicAdd(&acc[ka.z & (SPAN - 1)],
                      __half2float(__ushort_as_half((unsigned short)(av.y & 0xffffu))));
            atomicAdd(&acc[ka.w & (SPAN - 1)],
                      __half2float(__ushort_as_half((unsigned short)(av.y >> 16))));
            atomicAdd(&acc[kb.x & (SPAN - 1)],
                      __half2float(__ushort_as_half((unsigned short)(av.z & 0xffffu))));
            atomicAdd(&acc[kb.y & (SPAN - 1)],
                      __half2float(__ushort_as_half((unsigned short)(av.z >> 16))));
            atomicAdd(&acc[kb.z & (SPAN - 1)],
                      __half2float(__ushort_as_half((unsigned short)(av.w & 0xffffu))));
            atomicAdd(&acc[kb.w & (SPAN - 1)],
                      __half2float(__ushort_as_half((unsigned short)(av.w >> 16))));
        }
        for (unsigned i = nvec + tid; i < count; i += BBT)
            atomicAdd(&acc[kp[i] & (SPAN - 1)],
                      __half2float(__ushort_as_half(ap[i])));
    }
    __syncthreads();
    float* dst = rep + (size_t)seg * npad + (size_t)bkt * SPAN;
#pragma unroll
    for (int j = tid; j < SPAN; j += BBT) dst[j] = acc[j];
}

__global__ void k_norm(const float* __restrict__ rep,
                       const float* __restrict__ h,
                       float* __restrict__ dis, float* __restrict__ g,
                       int N, int npad) {
    int n = blockIdx.x * blockDim.x + threadIdx.x;
    if (n >= N) return;
    float d = 1.0f;               // self-loop weight
#pragma unroll
    for (int s = 0; s < SEG; ++s) d += rep[(size_t)s * npad + n];
    float si = rsqrtf(d);         // d >= 1 (attrs >= 0)
    dis[n] = si;
    g[n]   = si * h[n];
}

// grid: (SEG, nbkt). 8 edges/thread/iter for MLP.
__global__ void __launch_bounds__(BBT) k_bucket_scatter(
        const unsigned* __restrict__ g_cnt, const unsigned* __restrict__ keys,
        const __half* __restrict__ att16, const float* __restrict__ g,
        float* __restrict__ rep, int npad) {
    __shared__ float acc[SPAN];
    const int seg = blockIdx.x, bkt = blockIdx.y, tid = threadIdx.x;
#pragma unroll
    for (int j = tid; j < SPAN; j += BBT) acc[j] = 0.f;
    __syncthreads();
    const unsigned cnt = min(g_cnt[bkt], (unsigned)BCAP);
    const unsigned per = (((cnt + SEG - 1) / SEG) + 7u) & ~7u;   // x8-aligned
    const unsigned i0 = seg * per, i1 = min(cnt, i0 + per);
    const size_t base = (size_t)bkt * BCAP;
    if (i1 > i0) {
        const unsigned count = i1 - i0;
        const unsigned nvec  = count & ~7u;
        const unsigned* kp = keys + base + i0;
        const unsigned short* ap = (const unsigned short*)att16 + base + i0;
        for (unsigned o = tid << 3; o < nvec; o += BBT << 3) {
            uint4 ka = *(const uint4*)(kp + o);
            uint4 kb = *(const uint4*)(kp + o + 4);
            uint4 av = *(const uint4*)(const void*)(ap + o);   // 8 halves
            float g0 = g[ka.x >> SPAN_BITS];
            float g1 = g[ka.y >> SPAN_BITS];
            float g2 = g[ka.z >> SPAN_BITS];
            float g3 = g[ka.w >> SPAN_BITS];
            float g4 = g[kb.x >> SPAN_BITS];
            float g5 = g[kb.y >> SPAN_BITS];
            float g6 = g[kb.z >> SPAN_BITS];
            float g7 = g[kb.w >> SPAN_BITS];
            float a0 = __half2float(__ushort_as_half((unsigned short)(av.x & 0xffffu)));
            float a1 = __half2float(__ushort_as_half((unsigned short)(av.x >> 16)));
            float a2 = __half2float(__ushort_as_half((unsigned short)(av.y & 0xffffu)));
            float a3 = __half2float(__ushort_as_half((unsigned short)(av.y >> 16)));
            float a4 = __half2float(__ushort_as_half((unsigned short)(av.z & 0xffffu)));
            float a5 = __half2float(__ushort_as_half((unsigned short)(av.z >> 16)));
            float a6 = __half2float(__ushort_as_half((unsigned short)(av.w & 0xffffu)));
            float a7 = __half2float(__ushort_as_half((unsigned short)(av.w >> 16)));
            atomicAdd(&acc[ka.x & (SPAN - 1)], a0 * g0);
            atomicAdd(&acc[ka.y & (SPAN - 1)], a1 * g1);
            atomicAdd(&acc[ka.z & (SPAN - 1)], a2 * g2);
            atomicAdd(&acc[ka.w & (SPAN - 1)], a3 * g3);
            atomicAdd(&acc[kb.x & (SPAN - 1)], a4 * g4);
            atomicAdd(&acc[kb.y & (SPAN - 1)], a5 * g5);
            atomicAdd(&acc[kb.z & (SPAN - 1)], a6 * g6);
            atomicAdd(&acc[kb.w & (SPAN - 1)], a7 * g7);
        }
        for (unsigned i = nvec + tid; i < count; i += BBT) {
            unsigned k = kp[i];
            atomicAdd(&acc[k & (SPAN - 1)],
                      __half2float(__ushort_as_half(ap[i])) * g[k >> SPAN_BITS]);
        }
    }
    __syncthreads();
    float* dst = rep + (size_t)seg * npad + (size_t)bkt * SPAN;
#pragma unroll
    for (int j = tid; j < SPAN; j += BBT) dst[j] = acc[j];
}

__global__ void k_final(const float* __restrict__ rep,
                        const float* __restrict__ dis,
                        const float* __restrict__ g,
                        const float* __restrict__ b,
                        float* __restrict__ out, int N, int npad) {
    int n = blockIdx.x * blockDim.x + threadIdx.x;
    if (n >= N) return;
    float s = 0.f;
#pragma unroll
    for (int k = 0; k < SEG; ++k) s += rep[(size_t)k * npad + n];
    float v  = dis[n] * (s + g[n]) + b[0];   // edge msgs + self-loop dis^2*h
    float sp = (v > 20.0f) ? v : log1pf(expf(v));
    out[n] = v * tanhf(sp);
}

// ---- fallback (round-1 style) if ws is too small ----
__global__ void f_deg(const int* __restrict__ col, const float* __restrict__ attrs,
                      float* __restrict__ deg, int E) {
    int e = blockIdx.x * blockDim.x + threadIdx.x;
    if (e < E) atomicAdd(deg + col[e], attrs[e]);
}
__global__ void f_init(float* __restrict__ deg, int N) {
    int n = blockIdx.x * blockDim.x + threadIdx.x;
    if (n < N) deg[n] = 1.0f;
}
__global__ void f_norm(float* deg_dis, float* hg, float* __restrict__ acc, int N) {
    int n = blockIdx.x * blockDim.x + threadIdx.x;
    if (n >= N) return;
    float s = rsqrtf(deg_dis[n]);
    float gv = s * hg[n];
    deg_dis[n] = s; hg[n] = gv; acc[n] = s * gv;
}
__global__ void f_scatter(const int* __restrict__ row, const int* __restrict__ col,
                          const float* __restrict__ attrs, const float* __restrict__ g,
                          const float* __restrict__ dis, float* __restrict__ acc, int E) {
    int e = blockIdx.x * blockDim.x + threadIdx.x;
    if (e < E) atomicAdd(acc + col[e], attrs[e] * g[row[e]] * dis[col[e]]);
}
__global__ void f_mish(float* out, const float* __restrict__ b, int N) {
    int n = blockIdx.x * blockDim.x + threadIdx.x;
    if (n >= N) return;
    float v = out[n] + b[0];
    float sp = (v > 20.0f) ? v : log1pf(expf(v));
    out[n] = v * tanhf(sp);
}

extern "C" void kernel_launch(void* const* d_in, const int* in_sizes, int n_in,
                              void* d_out, int out_size, void* d_ws, size_t ws_size,
                              hipStream_t stream) {
    const float* x     = (const float*)d_in[0];
    const int*   ei    = (const int*)d_in[1];   // int32 (jax x64 disabled)
    const float* attrs = (const float*)d_in[2];
    const float* W     = (const float*)d_in[3];
    const float* bias  = (const float*)d_in[4];
    float* out = (float*)d_out;

    const int N = in_sizes[0] / NFEAT;
    const int E = in_sizes[1] / 2;
    const int* row = ei;        // sources
    const int* col = ei + E;    // targets

    const int nbkt = (N + SPAN - 1) / SPAN;     // 49
    const int npad = nbkt * SPAN;               // 200704

    const size_t need = (size_t)3 * N * 4             // h, dis, g
                      + (size_t)SEG * npad * 4        // replicas
                      + (size_t)MAXBKT * 4            // g_cnt
                      + (size_t)nbkt * BCAP * 6 + 256;
    const int BT = 256;

    if (ws_size >= need && nbkt <= MAXBKT) {
        float* h   = (float*)d_ws;                       // N
        float* dis = h + N;                              // N
        float* g   = dis + N;                            // N
        float* rep = g + N;                              // SEG*npad
        unsigned* g_cnt = (unsigned*)(rep + (size_t)SEG * npad);  // MAXBKT
        unsigned* keys  = g_cnt + MAXBKT;                // nbkt*BCAP
        __half* att16   = (__half*)(keys + (size_t)nbkt * BCAP);

        const int pgrid = (E + TILE - 1) / TILE;         // 2084 blocks

        k_zero_u32<<<1, 64, 0, stream>>>(g_cnt, MAXBKT);
        k_matvec<<<(N + 3) / 4, BT, 0, stream>>>(x, W, h, N);
        k_partition<<<pgrid, PBT, 0, stream>>>(row, col, attrs, g_cnt,
                                               keys, att16, E, nbkt);
        dim3 bg(SEG, nbkt);
        k_bucket_deg<<<bg, BBT, 0, stream>>>(g_cnt, keys, att16, rep, npad);
        k_norm<<<(N + BT - 1) / BT, BT, 0, stream>>>(rep, h, dis, g, N, npad);
        k_bucket_scatter<<<bg, BBT, 0, stream>>>(g_cnt, keys, att16, g, rep, npad);
        k_final<<<(N + BT - 1) / BT, BT, 0, stream>>>(rep, dis, g, bias, out, N, npad);
    } else {
        float* h   = (float*)d_ws;  // N, becomes g
        float* deg = h + N;         // N, becomes dis
        k_matvec<<<(N + 3) / 4, BT, 0, stream>>>(x, W, h, N);
        f_init<<<(N + BT - 1) / BT, BT, 0, stream>>>(deg, N);
        f_deg<<<(E + BT - 1) / BT, BT, 0, stream>>>(col, attrs, deg, E);
        f_norm<<<(N + BT - 1) / BT, BT, 0, stream>>>(deg, h, out, N);
        f_scatter<<<(E + BT - 1) / BT, BT, 0, stream>>>(row, col, attrs, h, deg, out, E);
        f_mish<<<(N + BT - 1) / BT, BT, 0, stream>>>(out, bias, N);
    }
}

// Round 6
// 562.205 us; speedup vs baseline: 1.0167x; 1.0167x over previous
//
#include <hip/hip_runtime.h>
#include <hip/hip_fp16.h>
#include <math.h>
#include <stdint.h>

// GCNConv(256 -> 1, edge_weight, self-loops, sym-norm) + Mish.
// N = 200000, E = 12.8M, F = 256.
//
// Round-9 recap: per-wave LDS histograms in k_partition were NEUTRAL
// (571.0 -> 571.6) -> LDS atomic contention was not the cost. Three
// neutral micro-rounds on the edge kernels.
//
// Round 10 theory: k_partition's remaining non-byte cost is the GLOBAL
// reservation atomics: 2084 blocks x 49 consecutive u32 counters = 102K
// device-scope RMWs all landing on TWO 128B cache lines. Memory-side
// same-line atomics serialize (~2.5-3.5 cyc/RMW => ~105-145 us), matching
// measured partition time across rounds and explaining every neutral fix.
// Fix: pad g_cnt to one counter per 128B line (stride 32 u32) -> 49
// parallel atomic streams. Single-variable change vs round 9.
//
//   0: zero g_cnt (padded)
//   A: h[n] = dot(x[n,:], W)                  (wave per node)
//   P: partition edges into 49 buckets        (per-wave LDS counting sort)
//   D: (bkt,seg): LDS acc += attr             -> rep[seg]   (plain store)
//   N: dis = rsqrt(1 + sum_seg rep); g = dis*h
//   S: (bkt,seg): LDS acc += attr * g[row]    -> rep[seg]   (reused)
//   F: out = mish(dis*(sum_seg rep + g) + b)

#define NFEAT 256
#define SPAN 4096
#define SPAN_BITS 12
#define MAXBKT 64
#define GC_STRIDE 32           // one g_cnt counter per 128B cache line
#define SEG 32
#define BCAP 266240            // mean 262144 + ~8 sigma (mult of 8)
#define TILE 6144              // edges per partition block (LDS-sorted tile)
#define PBT 512                // partition block threads
#define PWAVES (PBT / 64)      // 8 waves per partition block
#define BBT 512                // bucket-pass block threads

__global__ void k_zero_u32(unsigned* __restrict__ p, int n) {
    int i = blockIdx.x * blockDim.x + threadIdx.x;
    if (i < n) p[i] = 0u;
}

__global__ void k_matvec(const float* __restrict__ x,
                         const float* __restrict__ W,
                         float* __restrict__ h, int N) {
    int gid  = blockIdx.x * blockDim.x + threadIdx.x;
    int node = gid >> 6;          // one 64-lane wave per node
    int lane = gid & 63;
    if (node >= N) return;
    float4 xv = ((const float4*)(x + (size_t)node * NFEAT))[lane];
    float4 wv = ((const float4*)W)[lane];
    float s = xv.x * wv.x + xv.y * wv.y + xv.z * wv.z + xv.w * wv.w;
#pragma unroll
    for (int off = 32; off > 0; off >>= 1)
        s += __shfl_down(s, off, 64);
    if (lane == 0) h[node] = s;
}

// Block-local counting sort with per-wave histograms/cursors + coalesced
// run flush. LDS ~39.8 KB => 4 blocks/CU x 512 thr = 2048 threads/CU.
__global__ void __launch_bounds__(PBT) k_partition(
        const int* __restrict__ row, const int* __restrict__ col,
        const float* __restrict__ attrs,
        unsigned* __restrict__ g_cnt,
        unsigned* __restrict__ keys, __half* __restrict__ att16,
        int E, int nbkt) {
    __shared__ unsigned whist[PWAVES][MAXBKT];  // counts -> wave cursors
    __shared__ unsigned lhist[MAXBKT];          // block totals
    __shared__ unsigned lstart[MAXBKT];         // block-local run starts
    __shared__ unsigned lbase[MAXBKT];          // global run bases
    __shared__ unsigned lkey[TILE];
    __shared__ unsigned short latt[TILE];

    const int tid  = threadIdx.x;
    const int wave = tid >> 6;
    const int e0   = blockIdx.x * TILE;
    const int e1   = min(e0 + TILE, E);
    const int nv   = (e1 - e0) & ~3;     // vectorizable prefix (mult of 4)

    ((unsigned*)whist)[tid] = 0u;        // PBT==PWAVES*MAXBKT
    __syncthreads();
    // Pass 1: per-wave histogram (int4 col reads; atomics intra-wave only).
    unsigned* myh = whist[wave];
    for (int o = tid << 2; o < nv; o += PBT << 2) {
        int4 c4 = *(const int4*)(col + e0 + o);
        atomicAdd(&myh[((unsigned)c4.x) >> SPAN_BITS], 1u);
        atomicAdd(&myh[((unsigned)c4.y) >> SPAN_BITS], 1u);
        atomicAdd(&myh[((unsigned)c4.z) >> SPAN_BITS], 1u);
        atomicAdd(&myh[((unsigned)c4.w) >> SPAN_BITS], 1u);
    }
    for (int e = e0 + nv + tid; e < e1; e += PBT)
        atomicAdd(&myh[((unsigned)col[e]) >> SPAN_BITS], 1u);
    __syncthreads();
    // Per-bucket exclusive prefix over waves; whist[w][b] -> wave-local
    // start, lhist[b] -> block total. Thread b owns column b.
    if (tid < MAXBKT) {
        unsigned s = 0;
#pragma unroll
        for (int w = 0; w < PWAVES; ++w) {
            unsigned c = whist[w][tid];
            whist[w][tid] = s;
            s += c;
        }
        lhist[tid] = s;
    }
    __syncthreads();
    if (tid == 0) {                       // 49-element serial prefix: cheap
        unsigned s = 0;
        for (int b = 0; b < nbkt; ++b) { lstart[b] = s; s += lhist[b]; }
    }
    // Padded counters: one per 128B line -> 49 parallel atomic streams.
    if (tid < nbkt) lbase[tid] = atomicAdd(&g_cnt[tid * GC_STRIDE], lhist[tid]);
    __syncthreads();
    // Turn whist into absolute per-wave cursors.
    if ((tid & 63) < nbkt) whist[wave][tid & 63] += lstart[tid & 63];
    __syncthreads();

    // Pass 2: scatter into LDS via private wave cursors.
    for (int o = tid << 2; o < nv; o += PBT << 2) {
        const int e = e0 + o;
        int4   c4 = *(const int4*)(col + e);
        int4   r4 = *(const int4*)(row + e);
        float4 a4 = *(const float4*)(attrs + e);
        {
            unsigned c = (unsigned)c4.x, bkt = c >> SPAN_BITS;
            unsigned t = atomicAdd(&myh[bkt], 1u);
            lkey[t] = ((unsigned)r4.x << SPAN_BITS) | (c & (SPAN - 1));
            latt[t] = __half_as_ushort(__float2half(a4.x));
        }
        {
            unsigned c = (unsigned)c4.y, bkt = c >> SPAN_BITS;
            unsigned t = atomicAdd(&myh[bkt], 1u);
            lkey[t] = ((unsigned)r4.y << SPAN_BITS) | (c & (SPAN - 1));
            latt[t] = __half_as_ushort(__float2half(a4.y));
        }
        {
            unsigned c = (unsigned)c4.z, bkt = c >> SPAN_BITS;
            unsigned t = atomicAdd(&myh[bkt], 1u);
            lkey[t] = ((unsigned)r4.z << SPAN_BITS) | (c & (SPAN - 1));
            latt[t] = __half_as_ushort(__float2half(a4.z));
        }
        {
            unsigned c = (unsigned)c4.w, bkt = c >> SPAN_BITS;
            unsigned t = atomicAdd(&myh[bkt], 1u);
            lkey[t] = ((unsigned)r4.w << SPAN_BITS) | (c & (SPAN - 1));
            latt[t] = __half_as_ushort(__float2half(a4.w));
        }
    }
    for (int e = e0 + nv + tid; e < e1; e += PBT) {
        unsigned c   = (unsigned)col[e];
        unsigned bkt = c >> SPAN_BITS;
        unsigned t   = atomicAdd(&myh[bkt], 1u);
        lkey[t] = ((unsigned)row[e] << SPAN_BITS) | (c & (SPAN - 1));
        latt[t] = __half_as_ushort(__float2half(attrs[e]));
    }
    __syncthreads();

    // Flush runs: wave w handles buckets w, w+8, ... Each run (~125 edges)
    // is a contiguous LDS->global copy: 256 B key chunks + 128 B att chunks.
    const int lane = tid & 63;
    for (int b = wave; b < nbkt; b += PWAVES) {
        const unsigned cnt = lhist[b];
        const unsigned gb  = lbase[b];
        const unsigned ls  = lstart[b];
        const size_t base  = (size_t)b * BCAP;
        for (unsigned i = lane; i < cnt; i += 64) {
            unsigned t = gb + i;
            if (t < BCAP) {              // never hit for this input; OOB guard
                keys[base + t]  = lkey[ls + i];
                att16[base + t] = __ushort_as_half(latt[ls + i]);
            }
        }
    }
}

// grid: (SEG, nbkt). 8 edges/thread/iter. Segment bounds padded to x8 so
// uint4 loads stay aligned. rep layout: rep[seg * npad + node].
__global__ void __launch_bounds__(BBT) k_bucket_deg(
        const unsigned* __restrict__ g_cnt, const unsigned* __restrict__ keys,
        const __half* __restrict__ att16, float* __restrict__ rep, int npad) {
    __shared__ float acc[SPAN];
    const int seg = blockIdx.x, bkt = blockIdx.y, tid = threadIdx.x;
#pragma unroll
    for (int j = tid; j < SPAN; j += BBT) acc[j] = 0.f;
    __syncthreads();
    const unsigned cnt = min(g_cnt[bkt * GC_STRIDE], (unsigned)BCAP);
    const unsigned per = (((cnt + SEG - 1) / SEG) + 7u) & ~7u;   // x8-aligned
    const unsigned i0 = seg * per, i1 = min(cnt, i0 + per);
    const size_t base = (size_t)bkt * BCAP;
    if (i1 > i0) {
        const unsigned count = i1 - i0;
        const unsigned nvec  = count & ~7u;
        const unsigned* kp = keys + base + i0;
        const unsigned short* ap = (const unsigned short*)att16 + base + i0;
        for (unsigned o = tid << 3; o < nvec; o += BBT << 3) {
            uint4 ka = *(const uint4*)(kp + o);
            uint4 kb = *(const uint4*)(kp + o + 4);
            uint4 av = *(const uint4*)(const void*)(ap + o);   // 8 halves
            atomicAdd(&acc[ka.x & (SPAN - 1)],
                      __half2float(__ushort_as_half((unsigned short)(av.x & 0xffffu))));
            atomicAdd(&acc[ka.y & (SPAN - 1)],
                      __half2float(__ushort_as_half((unsigned short)(av.x >> 16))));
            atomicAdd(&acc[ka.z & (SPAN - 1)],
                      __half2float(__ushort_as_half((unsigned short)(av.y & 0xffffu))));
            atomicAdd(&acc[ka.w & (SPAN - 1)],
                      __half2float(__ushort_as_half((unsigned short)(av.y >> 16))));
            atomicAdd(&acc[kb.x & (SPAN - 1)],
                      __half2float(__ushort_as_half((unsigned short)(av.z & 0xffffu))));
            atomicAdd(&acc[kb.y & (SPAN - 1)],
                      __half2float(__ushort_as_half((unsigned short)(av.z >> 16))));
            atomicAdd(&acc[kb.z & (SPAN - 1)],
                      __half2float(__ushort_as_half((unsigned short)(av.w & 0xffffu))));
            atomicAdd(&acc[kb.w & (SPAN - 1)],
                      __half2float(__ushort_as_half((unsigned short)(av.w >> 16))));
        }
        for (unsigned i = nvec + tid; i < count; i += BBT)
            atomicAdd(&acc[kp[i] & (SPAN - 1)],
                      __half2float(__ushort_as_half(ap[i])));
    }
    __syncthreads();
    float* dst = rep + (size_t)seg * npad + (size_t)bkt * SPAN;
#pragma unroll
    for (int j = tid; j < SPAN; j += BBT) dst[j] = acc[j];
}

__global__ void k_norm(const float* __restrict__ rep,
                       const float* __restrict__ h,
                       float* __restrict__ dis, float* __restrict__ g,
                       int N, int npad) {
    int n = blockIdx.x * blockDim.x + threadIdx.x;
    if (n >= N) return;
    float d = 1.0f;               // self-loop weight
#pragma unroll
    for (int s = 0; s < SEG; ++s) d += rep[(size_t)s * npad + n];
    float si = rsqrtf(d);         // d >= 1 (attrs >= 0)
    dis[n] = si;
    g[n]   = si * h[n];
}

// grid: (SEG, nbkt). 8 edges/thread/iter for MLP.
__global__ void __launch_bounds__(BBT) k_bucket_scatter(
        const unsigned* __restrict__ g_cnt, const unsigned* __restrict__ keys,
        const __half* __restrict__ att16, const float* __restrict__ g,
        float* __restrict__ rep, int npad) {
    __shared__ float acc[SPAN];
    const int seg = blockIdx.x, bkt = blockIdx.y, tid = threadIdx.x;
#pragma unroll
    for (int j = tid; j < SPAN; j += BBT) acc[j] = 0.f;
    __syncthreads();
    const unsigned cnt = min(g_cnt[bkt * GC_STRIDE], (unsigned)BCAP);
    const unsigned per = (((cnt + SEG - 1) / SEG) + 7u) & ~7u;   // x8-aligned
    const unsigned i0 = seg * per, i1 = min(cnt, i0 + per);
    const size_t base = (size_t)bkt * BCAP;
    if (i1 > i0) {
        const unsigned count = i1 - i0;
        const unsigned nvec  = count & ~7u;
        const unsigned* kp = keys + base + i0;
        const unsigned short* ap = (const unsigned short*)att16 + base + i0;
        for (unsigned o = tid << 3; o < nvec; o += BBT << 3) {
            uint4 ka = *(const uint4*)(kp + o);
            uint4 kb = *(const uint4*)(kp + o + 4);
            uint4 av = *(const uint4*)(const void*)(ap + o);   // 8 halves
            float g0 = g[ka.x >> SPAN_BITS];
            float g1 = g[ka.y >> SPAN_BITS];
            float g2 = g[ka.z >> SPAN_BITS];
            float g3 = g[ka.w >> SPAN_BITS];
            float g4 = g[kb.x >> SPAN_BITS];
            float g5 = g[kb.y >> SPAN_BITS];
            float g6 = g[kb.z >> SPAN_BITS];
            float g7 = g[kb.w >> SPAN_BITS];
            float a0 = __half2float(__ushort_as_half((unsigned short)(av.x & 0xffffu)));
            float a1 = __half2float(__ushort_as_half((unsigned short)(av.x >> 16)));
            float a2 = __half2float(__ushort_as_half((unsigned short)(av.y & 0xffffu)));
            float a3 = __half2float(__ushort_as_half((unsigned short)(av.y >> 16)));
            float a4 = __half2float(__ushort_as_half((unsigned short)(av.z & 0xffffu)));
            float a5 = __half2float(__ushort_as_half((unsigned short)(av.z >> 16)));
            float a6 = __half2float(__ushort_as_half((unsigned short)(av.w & 0xffffu)));
            float a7 = __half2float(__ushort_as_half((unsigned short)(av.w >> 16)));
            atomicAdd(&acc[ka.x & (SPAN - 1)], a0 * g0);
            atomicAdd(&acc[ka.y & (SPAN - 1)], a1 * g1);
            atomicAdd(&acc[ka.z & (SPAN - 1)], a2 * g2);
            atomicAdd(&acc[ka.w & (SPAN - 1)], a3 * g3);
            atomicAdd(&acc[kb.x & (SPAN - 1)], a4 * g4);
            atomicAdd(&acc[kb.y & (SPAN - 1)], a5 * g5);
            atomicAdd(&acc[kb.z & (SPAN - 1)], a6 * g6);
            atomicAdd(&acc[kb.w & (SPAN - 1)], a7 * g7);
        }
        for (unsigned i = nvec + tid; i < count; i += BBT) {
            unsigned k = kp[i];
            atomicAdd(&acc[k & (SPAN - 1)],
                      __half2float(__ushort_as_half(ap[i])) * g[k >> SPAN_BITS]);
        }
    }
    __syncthreads();
    float* dst = rep + (size_t)seg * npad + (size_t)bkt * SPAN;
#pragma unroll
    for (int j = tid; j < SPAN; j += BBT) dst[j] = acc[j];
}

__global__ void k_final(const float* __restrict__ rep,
                        const float* __restrict__ dis,
                        const float* __restrict__ g,
                        const float* __restrict__ b,
                        float* __restrict__ out, int N, int npad) {
    int n = blockIdx.x * blockDim.x + threadIdx.x;
    if (n >= N) return;
    float s = 0.f;
#pragma unroll
    for (int k = 0; k < SEG; ++k) s += rep[(size_t)k * npad + n];
    float v  = dis[n] * (s + g[n]) + b[0];   // edge msgs + self-loop dis^2*h
    float sp = (v > 20.0f) ? v : log1pf(expf(v));
    out[n] = v * tanhf(sp);
}

// ---- fallback (round-1 style) if ws is too small ----
__global__ void f_deg(const int* __restrict__ col, const float* __restrict__ attrs,
                      float* __restrict__ deg, int E) {
    int e = blockIdx.x * blockDim.x + threadIdx.x;
    if (e < E) atomicAdd(deg + col[e], attrs[e]);
}
__global__ void f_init(float* __restrict__ deg, int N) {
    int n = blockIdx.x * blockDim.x + threadIdx.x;
    if (n < N) deg[n] = 1.0f;
}
__global__ void f_norm(float* deg_dis, float* hg, float* __restrict__ acc, int N) {
    int n = blockIdx.x * blockDim.x + threadIdx.x;
    if (n >= N) return;
    float s = rsqrtf(deg_dis[n]);
    float gv = s * hg[n];
    deg_dis[n] = s; hg[n] = gv; acc[n] = s * gv;
}
__global__ void f_scatter(const int* __restrict__ row, const int* __restrict__ col,
                          const float* __restrict__ attrs, const float* __restrict__ g,
                          const float* __restrict__ dis, float* __restrict__ acc, int E) {
    int e = blockIdx.x * blockDim.x + threadIdx.x;
    if (e < E) atomicAdd(acc + col[e], attrs[e] * g[row[e]] * dis[col[e]]);
}
__global__ void f_mish(float* out, const float* __restrict__ b, int N) {
    int n = blockIdx.x * blockDim.x + threadIdx.x;
    if (n >= N) return;
    float v = out[n] + b[0];
    float sp = (v > 20.0f) ? v : log1pf(expf(v));
    out[n] = v * tanhf(sp);
}

extern "C" void kernel_launch(void* const* d_in, const int* in_sizes, int n_in,
                              void* d_out, int out_size, void* d_ws, size_t ws_size,
                              hipStream_t stream) {
    const float* x     = (const float*)d_in[0];
    const int*   ei    = (const int*)d_in[1];   // int32 (jax x64 disabled)
    const float* attrs = (const float*)d_in[2];
    const float* W     = (const float*)d_in[3];
    const float* bias  = (const float*)d_in[4];
    float* out = (float*)d_out;

    const int N = in_sizes[0] / NFEAT;
    const int E = in_sizes[1] / 2;
    const int* row = ei;        // sources
    const int* col = ei + E;    // targets

    const int nbkt = (N + SPAN - 1) / SPAN;     // 49
    const int npad = nbkt * SPAN;               // 200704

    const size_t need = (size_t)3 * N * 4             // h, dis, g
                      + (size_t)SEG * npad * 4        // replicas
                      + (size_t)MAXBKT * GC_STRIDE * 4  // padded g_cnt
                      + (size_t)nbkt * BCAP * 6 + 256;
    const int BT = 256;

    if (ws_size >= need && nbkt <= MAXBKT) {
        float* h   = (float*)d_ws;                       // N
        float* dis = h + N;                              // N
        float* g   = dis + N;                            // N
        float* rep = g + N;                              // SEG*npad
        unsigned* g_cnt = (unsigned*)(rep + (size_t)SEG * npad);  // MAXBKT*32
        unsigned* keys  = g_cnt + MAXBKT * GC_STRIDE;    // nbkt*BCAP
        __half* att16   = (__half*)(keys + (size_t)nbkt * BCAP);

        const int pgrid = (E + TILE - 1) / TILE;         // 2084 blocks

        k_zero_u32<<<(MAXBKT * GC_STRIDE + 63) / 64, 64, 0, stream>>>(
            g_cnt, MAXBKT * GC_STRIDE);
        k_matvec<<<(N + 3) / 4, BT, 0, stream>>>(x, W, h, N);
        k_partition<<<pgrid, PBT, 0, stream>>>(row, col, attrs, g_cnt,
                                               keys, att16, E, nbkt);
        dim3 bg(SEG, nbkt);
        k_bucket_deg<<<bg, BBT, 0, stream>>>(g_cnt, keys, att16, rep, npad);
        k_norm<<<(N + BT - 1) / BT, BT, 0, stream>>>(rep, h, dis, g, N, npad);
        k_bucket_scatter<<<bg, BBT, 0, stream>>>(g_cnt, keys, att16, g, rep, npad);
        k_final<<<(N + BT - 1) / BT, BT, 0, stream>>>(rep, dis, g, bias, out, N, npad);
    } else {
        float* h   = (float*)d_ws;  // N, becomes g
        float* deg = h + N;         // N, becomes dis
        k_matvec<<<(N + 3) / 4, BT, 0, stream>>>(x, W, h, N);
        f_init<<<(N + BT - 1) / BT, BT, 0, stream>>>(deg, N);
        f_deg<<<(E + BT - 1) / BT, BT, 0, stream>>>(col, attrs, deg, E);
        f_norm<<<(N + BT - 1) / BT, BT, 0, stream>>>(deg, h, out, N);
        f_scatter<<<(E + BT - 1) / BT, BT, 0, stream>>>(row, col, attrs, h, deg, out, E);
        f_mish<<<(N + BT - 1) / BT, BT, 0, stream>>>(out, bias, N);
    }
}